// Round 1
// baseline (215.567 us; speedup 1.0000x reference)
//
#include <hip/hip_runtime.h>
#include <hip/hip_bf16.h>

// Problem: out = X + s*(relu(A_hat @ (X @ W_agg)) - X), s = sigmoid(wg)*sigmoid(wl)
// Sizes: X[8192,256] f32, A_hat[8192,8192] f32, W_agg[256,256] f32. Out f32 [8192,256].
// Strategy: associativity (A@X)@W == A@(X@W). Small GEMM first (XW), then one
// HBM-bound big GEMM (A 268MB read once) in bf16 MFMA with fused epilogue.

typedef __attribute__((ext_vector_type(4))) float f32x4;
typedef __attribute__((ext_vector_type(8))) __bf16 bf16x8;

#define GLOBAL_AS __attribute__((address_space(1)))
#define LDS_AS __attribute__((address_space(3)))

static __device__ __forceinline__ void gload_lds16(const void* gsrc, void* lds) {
  __builtin_amdgcn_global_load_lds((const GLOBAL_AS void*)gsrc, (LDS_AS void*)lds, 16, 0, 0);
}

static __device__ __forceinline__ unsigned short f2bf_bits(float f) {
  __bf16 h = (__bf16)f;
  return __builtin_bit_cast(unsigned short, h);
}

// ---------------- prep: s vector + W^T (bf16, tiled [k/32][n=256][32]) -------------
__global__ void prep_kernel(const float* __restrict__ W,
                            const float* __restrict__ wg,
                            const float* __restrict__ wl,
                            unsigned short* __restrict__ WT,  // [8][256][32] bf16
                            float* __restrict__ s) {
  int tid = blockIdx.x * 256 + threadIdx.x;  // 0..65535
  int k = tid >> 8, n = tid & 255;
  float w = W[tid];  // W[k][n]
  int kt = k >> 5, kloc = k & 31;
  WT[kt * 8192 + n * 32 + kloc] = f2bf_bits(w);
  if (tid < 8192) {
    float sg = 1.0f / (1.0f + expf(-wg[0]));
    float sl = 1.0f / (1.0f + expf(-wl[tid]));
    s[tid] = sg * sl;
  }
}

// ---------------- gemm0: XW = X @ W, write XW^T bf16 tiled [m/32][n=256][32] -------
// BM=32 (rows), BN=128, BK=32, 256 threads = 4 waves (each 32M x 32N).
__global__ __launch_bounds__(256, 2) void gemm_xw(
    const float* __restrict__ X,              // [8192][256]
    const unsigned short* __restrict__ WT,    // tiled [8][256][32]
    unsigned short* __restrict__ XWT) {       // tiled [256][256][32]
  __shared__ float As[2][32 * 32];            // f32 A tile (XOR-swizzled 16B slots)
  __shared__ unsigned short Bs[2][128 * 32];  // bf16 B half-tile (linear)

  const int bm = blockIdx.x & 255;
  const int bn = blockIdx.x >> 8;
  const int m0 = bm * 32;
  const int tid = threadIdx.x;
  const int w = tid >> 6;
  const int l = tid & 63;
  const int lr = l & 15;
  const int lq = l >> 4;

  // A staging: wave w stages 1KB: dest byte p = w*1024 + l*16 (linear in LDS)
  const int pA = w * 1024 + l * 16;
  const int rA = pA >> 7;            // dest row (128B rows)
  const int qA = (pA >> 4) & 7;      // dest 16B slot
  const int ssA = qA ^ (rA & 7);     // pre-swizzled source slot
  const char* Asrc0 = (const char*)X + (size_t)(m0 + rA) * 1024 + ssA * 16;
  const char* Bsrc0 = (const char*)WT + bn * 8192 + w * 2048 + l * 16;

  f32x4 acc[2][2];
#pragma unroll
  for (int i = 0; i < 2; ++i)
#pragma unroll
    for (int j = 0; j < 2; ++j) acc[i][j] = (f32x4){0.f, 0.f, 0.f, 0.f};

  auto stage = [&](int t, int buf) {
    gload_lds16(Asrc0 + (size_t)t * 128, (char*)&As[buf][0] + w * 1024);
    const char* bs = Bsrc0 + (size_t)t * 16384;
    gload_lds16(bs, (char*)&Bs[buf][0] + w * 2048);
    gload_lds16(bs + 1024, (char*)&Bs[buf][0] + w * 2048 + 1024);
  };

  auto compute = [&](int buf) {
    bf16x8 af[2];
#pragma unroll
    for (int mi = 0; mi < 2; ++mi) {
      int r = mi * 16 + lr;
      const float* ap = &As[buf][r * 32];
      int s0 = (2 * lq) ^ (r & 7);
      int s1 = (2 * lq + 1) ^ (r & 7);
      f32x4 a0 = *(const f32x4*)(ap + s0 * 4);
      f32x4 a1 = *(const f32x4*)(ap + s1 * 4);
      bf16x8 v;
      v[0] = (__bf16)a0.x; v[1] = (__bf16)a0.y; v[2] = (__bf16)a0.z; v[3] = (__bf16)a0.w;
      v[4] = (__bf16)a1.x; v[5] = (__bf16)a1.y; v[6] = (__bf16)a1.z; v[7] = (__bf16)a1.w;
      af[mi] = v;
    }
    bf16x8 bfr[2];
#pragma unroll
    for (int ni = 0; ni < 2; ++ni) {
      int row = w * 32 + ni * 16 + lr;
      bfr[ni] = *(const bf16x8*)(&Bs[buf][row * 32 + lq * 8]);
    }
#pragma unroll
    for (int mi = 0; mi < 2; ++mi)
#pragma unroll
      for (int ni = 0; ni < 2; ++ni)
        acc[mi][ni] = __builtin_amdgcn_mfma_f32_16x16x32_bf16(af[mi], bfr[ni], acc[mi][ni], 0, 0, 0);
  };

  stage(0, 0);
  __syncthreads();
  for (int t = 0; t < 8; ++t) {
    int cur = t & 1;
    if (t + 1 < 8) stage(t + 1, cur ^ 1);
    compute(cur);
    __syncthreads();
  }

  // epilogue: write XW^T bf16 into tile bm: pos = n*32 + (m%32)
  unsigned short* dst = XWT + bm * 8192;
#pragma unroll
  for (int mi = 0; mi < 2; ++mi)
#pragma unroll
    for (int ni = 0; ni < 2; ++ni) {
      f32x4 z = acc[mi][ni];
      int n = bn * 128 + w * 32 + ni * 16 + lr;
      int mloc = mi * 16 + lq * 4;
      ushort4 u;
      u.x = f2bf_bits(z[0]); u.y = f2bf_bits(z[1]);
      u.z = f2bf_bits(z[2]); u.w = f2bf_bits(z[3]);
      *(ushort4*)(dst + n * 32 + mloc) = u;
    }
}

// ---------------- gemm1: Z = A_hat @ XW; out = X + s*(relu(Z) - X) ------------------
// BM=32, BN=128, BK=32, 256 threads, grid 512 (bid_m = b&255 so blocks b and b+256
// share A rows and land on the same XCD under round-robin dispatch).
__global__ __launch_bounds__(256, 2) void gemm_main(
    const float* __restrict__ A,              // [8192][8192]
    const unsigned short* __restrict__ B,     // XWT tiled [256][256][32]
    const float* __restrict__ X,              // [8192][256]
    const float* __restrict__ s,              // [8192]
    float* __restrict__ out) {                // [8192][256]
  __shared__ float As[2][32 * 32];
  __shared__ unsigned short Bs[2][128 * 32];

  const int bm = blockIdx.x & 255;
  const int bn = blockIdx.x >> 8;
  const int m0 = bm * 32;
  const int tid = threadIdx.x;
  const int w = tid >> 6;
  const int l = tid & 63;
  const int lr = l & 15;
  const int lq = l >> 4;

  const int pA = w * 1024 + l * 16;
  const int rA = pA >> 7;
  const int qA = (pA >> 4) & 7;
  const int ssA = qA ^ (rA & 7);
  const char* Asrc0 = (const char*)A + (size_t)(m0 + rA) * 32768 + ssA * 16;
  const char* Bsrc0 = (const char*)B + bn * 8192 + w * 2048 + l * 16;

  f32x4 acc[2][2];
#pragma unroll
  for (int i = 0; i < 2; ++i)
#pragma unroll
    for (int j = 0; j < 2; ++j) acc[i][j] = (f32x4){0.f, 0.f, 0.f, 0.f};

  auto stage = [&](int t, int buf) {
    gload_lds16(Asrc0 + (size_t)t * 128, (char*)&As[buf][0] + w * 1024);
    const char* bs = Bsrc0 + (size_t)t * 16384;
    gload_lds16(bs, (char*)&Bs[buf][0] + w * 2048);
    gload_lds16(bs + 1024, (char*)&Bs[buf][0] + w * 2048 + 1024);
  };

  auto compute = [&](int buf) {
    bf16x8 af[2];
#pragma unroll
    for (int mi = 0; mi < 2; ++mi) {
      int r = mi * 16 + lr;
      const float* ap = &As[buf][r * 32];
      int s0 = (2 * lq) ^ (r & 7);
      int s1 = (2 * lq + 1) ^ (r & 7);
      f32x4 a0 = *(const f32x4*)(ap + s0 * 4);
      f32x4 a1 = *(const f32x4*)(ap + s1 * 4);
      bf16x8 v;
      v[0] = (__bf16)a0.x; v[1] = (__bf16)a0.y; v[2] = (__bf16)a0.z; v[3] = (__bf16)a0.w;
      v[4] = (__bf16)a1.x; v[5] = (__bf16)a1.y; v[6] = (__bf16)a1.z; v[7] = (__bf16)a1.w;
      af[mi] = v;
    }
    bf16x8 bfr[2];
#pragma unroll
    for (int ni = 0; ni < 2; ++ni) {
      int row = w * 32 + ni * 16 + lr;
      bfr[ni] = *(const bf16x8*)(&Bs[buf][row * 32 + lq * 8]);
    }
#pragma unroll
    for (int mi = 0; mi < 2; ++mi)
#pragma unroll
      for (int ni = 0; ni < 2; ++ni)
        acc[mi][ni] = __builtin_amdgcn_mfma_f32_16x16x32_bf16(af[mi], bfr[ni], acc[mi][ni], 0, 0, 0);
  };

  stage(0, 0);
  __syncthreads();
  for (int t = 0; t < 256; ++t) {
    int cur = t & 1;
    if (t + 1 < 256) stage(t + 1, cur ^ 1);
    compute(cur);
    __syncthreads();
  }

  // fused epilogue: out = x + s*(relu(z) - x)
#pragma unroll
  for (int mi = 0; mi < 2; ++mi)
#pragma unroll
    for (int ni = 0; ni < 2; ++ni) {
      f32x4 z = acc[mi][ni];
      int n = bn * 128 + w * 32 + ni * 16 + lr;
#pragma unroll
      for (int i = 0; i < 4; ++i) {
        int m = m0 + mi * 16 + lq * 4 + i;
        float x = X[m * 256 + n];
        float sv = s[m];
        float rl = fmaxf(z[i], 0.f);
        out[m * 256 + n] = x + sv * (rl - x);
      }
    }
}

extern "C" void kernel_launch(void* const* d_in, const int* in_sizes, int n_in,
                              void* d_out, int out_size, void* d_ws, size_t ws_size,
                              hipStream_t stream) {
  const float* X = (const float*)d_in[0];
  const float* A = (const float*)d_in[1];
  const float* wg = (const float*)d_in[2];
  const float* wl = (const float*)d_in[3];
  const float* W = (const float*)d_in[4];
  float* out = (float*)d_out;

  // workspace layout (bytes): XWT tiled bf16 [256][256][32] = 4 MiB, WT tiled bf16
  // [8][256][32] = 128 KiB, s f32 [8192] = 32 KiB.  total ~4.36 MB
  unsigned short* XWT = (unsigned short*)d_ws;
  unsigned short* WT = (unsigned short*)((char*)d_ws + 4194304);
  float* s = (float*)((char*)d_ws + 4194304 + 131072);

  prep_kernel<<<256, 256, 0, stream>>>(W, wg, wl, WT, s);
  gemm_xw<<<512, 256, 0, stream>>>(X, WT, XWT);
  gemm_main<<<512, 256, 0, stream>>>(A, XWT, X, s, out);
}